// Round 1
// baseline (121.943 us; speedup 1.0000x reference)
//
#include <hip/hip_runtime.h>

// EncoderBlock, fully fused: gather(x, idx) -> per-o GEMM (512x128 @ K=512)
// + bias -> BatchNorm over B=512 -> SiLU -> out, in ONE kernel.
//
// One block per output group o (64 blocks x 1024 threads = 16 waves).
// Each wave owns a 64x64 output sub-tile (acc[4][4] f32x4 = 64 VGPR).
// BN stats: per-wave shfl reduction over its 64 rows -> LDS reduction over
// the 8 row-wave-groups -> scale/shift in LDS -> in-register normalize+SiLU
// -> single fp32 store. No y intermediate, no psum/psq, no second kernel.

typedef __attribute__((ext_vector_type(8))) __bf16 bf16x8;
typedef __attribute__((ext_vector_type(4))) __bf16 bf16x4;
typedef __attribute__((ext_vector_type(4))) float  f32x4;

#define B_SZ   512
#define N_IN   64
#define D_IN   128
#define N_O    64
#define D_O    128
#define FEAT   (N_O * D_O)     // 8192
#define LDA    40              // LDS row stride (bf16 elems): 80B, 16B-aligned

__global__ __launch_bounds__(1024, 4)
void fused_encoder_kernel(const float* __restrict__ x, const float* __restrict__ W,
                          const float* __restrict__ bias, const float* __restrict__ gamma,
                          const float* __restrict__ beta, const int* __restrict__ idxp,
                          float* __restrict__ out)
{
    // A tile: xg rows [512 b][32 k] k-major.  B tile: W^T [128 e][32 k] k-major.
    __shared__ __bf16 Alds[512 * LDA];   // 40 KiB
    __shared__ __bf16 Blds[128 * LDA];   // 10 KiB
    __shared__ float  Sred[8 * 128];     // 4 KiB  per-wave-row-group column sums
    __shared__ float  Qred[8 * 128];     // 4 KiB  ... sumsq
    __shared__ float  sscale[128];
    __shared__ float  sshift[128];

    const int o    = blockIdx.x;        // output group
    const int tid  = threadIdx.x;
    const int wave = tid >> 6;          // 0..15
    const int lane = tid & 63;
    const int wr   = wave >> 1;         // row group: rows 64*wr..64*wr+63
    const int wc   = wave & 1;          // col group: cols 64*wc..64*wc+63
    const int lam  = lane & 15;
    const int quad = lane >> 4;

    int rsel[4];
#pragma unroll
    for (int k = 0; k < 4; ++k) rsel[k] = idxp[o * 4 + k];

    const f32x4 zero4 = {0.f, 0.f, 0.f, 0.f};
    f32x4 acc[4][4];
#pragma unroll
    for (int mi = 0; mi < 4; ++mi)
#pragma unroll
        for (int ni = 0; ni < 4; ++ni) acc[mi][ni] = zero4;

    // A staging: 2 threads per batch row, 16 floats each (512 rows x 32 k)
    const int m_a = tid >> 1;           // 0..511
    const int ca  = (tid & 1) * 16;
    // B staging: 1 bf16x4 per thread (128 e x 32 k), k-contiguous LDS write
    const int e_b = tid & 127;
    const int dgb = tid >> 7;           // 0..7 -> k-offset dgb*4

    for (int kk = 0; kk < 16; ++kk) {
        const int kidx = kk >> 2;          // which gathered row
        const int d0   = (kk & 3) * 32;    // d-chunk within that row
        const int r    = rsel[kidx];

        // ---- global loads + cvt into registers (before barrier) ----
        const float* xa = x + ((m_a * N_IN + r) * D_IN + d0 + ca);
        f32x4 xv0 = *(const f32x4*)(xa + 0);
        f32x4 xv1 = *(const f32x4*)(xa + 4);
        f32x4 xv2 = *(const f32x4*)(xa + 8);
        f32x4 xv3 = *(const f32x4*)(xa + 12);
        bf16x8 p0, p1;
        p0[0] = (__bf16)xv0[0]; p0[1] = (__bf16)xv0[1];
        p0[2] = (__bf16)xv0[2]; p0[3] = (__bf16)xv0[3];
        p0[4] = (__bf16)xv1[0]; p0[5] = (__bf16)xv1[1];
        p0[6] = (__bf16)xv1[2]; p0[7] = (__bf16)xv1[3];
        p1[0] = (__bf16)xv2[0]; p1[1] = (__bf16)xv2[1];
        p1[2] = (__bf16)xv2[2]; p1[3] = (__bf16)xv2[3];
        p1[4] = (__bf16)xv3[0]; p1[5] = (__bf16)xv3[1];
        p1[6] = (__bf16)xv3[2]; p1[7] = (__bf16)xv3[3];

        // B: 4 strided-d scalar loads (coalesced across lanes in e)
        const float* wp = W + (((o * 4 + kidx) * 128 + (d0 + dgb * 4)) * 128 + e_b);
        bf16x4 wb;
        wb[0] = (__bf16)wp[0];
        wb[1] = (__bf16)wp[128];
        wb[2] = (__bf16)wp[256];
        wb[3] = (__bf16)wp[384];

        __syncthreads();   // previous iteration's MFMA frag reads done
        *(bf16x8*)&Alds[m_a * LDA + ca]     = p0;
        *(bf16x8*)&Alds[m_a * LDA + ca + 8] = p1;
        *(bf16x4*)&Blds[e_b * LDA + dgb * 4] = wb;
        __syncthreads();

        // ---- MFMA: A[m=lam][k=quad*8+j], B[k=quad*8+j][n=lam] ----
        bf16x8 af[4], bfv[4];
#pragma unroll
        for (int mi = 0; mi < 4; ++mi)
            af[mi] = *(const bf16x8*)&Alds[(wr * 64 + mi * 16 + lam) * LDA + quad * 8];
#pragma unroll
        for (int ni = 0; ni < 4; ++ni)
            bfv[ni] = *(const bf16x8*)&Blds[(wc * 64 + ni * 16 + lam) * LDA + quad * 8];
#pragma unroll
        for (int mi = 0; mi < 4; ++mi)
#pragma unroll
            for (int ni = 0; ni < 4; ++ni)
                acc[mi][ni] = __builtin_amdgcn_mfma_f32_16x16x32_bf16(
                    af[mi], bfv[ni], acc[mi][ni], 0, 0, 0);
    }

    // ---- bias (before BN, matching reference) ----
    const int nbase = wc * 64;
    float bvals[4];
#pragma unroll
    for (int ni = 0; ni < 4; ++ni)
        bvals[ni] = bias[o * 128 + nbase + ni * 16 + lam];
#pragma unroll
    for (int mi = 0; mi < 4; ++mi)
#pragma unroll
        for (int ni = 0; ni < 4; ++ni)
#pragma unroll
            for (int rr = 0; rr < 4; ++rr) acc[mi][ni][rr] += bvals[ni];

    // ---- per-column stats: wave-local 64-row sums -> LDS over 8 wr groups ----
#pragma unroll
    for (int ni = 0; ni < 4; ++ni) {
        float s = 0.f, q = 0.f;
#pragma unroll
        for (int mi = 0; mi < 4; ++mi)
#pragma unroll
            for (int rr = 0; rr < 4; ++rr) {
                const float v = acc[mi][ni][rr];
                s += v; q += v * v;
            }
        s += __shfl_xor(s, 16); s += __shfl_xor(s, 32);
        q += __shfl_xor(q, 16); q += __shfl_xor(q, 32);
        if (quad == 0) {
            const int e = nbase + ni * 16 + lam;
            Sred[wr * 128 + e] = s;
            Qred[wr * 128 + e] = q;
        }
    }
    __syncthreads();

    if (tid < 128) {
        float s = 0.f, q = 0.f;
#pragma unroll
        for (int sl = 0; sl < 8; ++sl) {
            s += Sred[sl * 128 + tid];
            q += Qred[sl * 128 + tid];
        }
        const float mean = s * (1.0f / 512.0f);
        const float var  = q * (1.0f / 512.0f) - mean * mean;
        const float rstd = rsqrtf(var + 1e-5f);
        const float sc   = rstd * gamma[o * 128 + tid];
        sscale[tid] = sc;
        sshift[tid] = beta[o * 128 + tid] - mean * sc;
    }
    __syncthreads();

    // ---- normalize + SiLU in-register, single fp32 store ----
#pragma unroll
    for (int mi = 0; mi < 4; ++mi) {
        const int rowb = wr * 64 + mi * 16 + quad * 4;
#pragma unroll
        for (int ni = 0; ni < 4; ++ni) {
            const int col = nbase + ni * 16 + lam;
            const float sc = sscale[col];
            const float sh = sshift[col];
#pragma unroll
            for (int rr = 0; rr < 4; ++rr) {
                const float xn = acc[mi][ni][rr] * sc + sh;
                const float sg = 1.0f / (1.0f + __expf(-xn));
                out[(rowb + rr) * FEAT + o * 128 + col] = xn * sg;
            }
        }
    }
}

extern "C" void kernel_launch(void* const* d_in, const int* in_sizes, int n_in,
                              void* d_out, int out_size, void* d_ws, size_t ws_size,
                              hipStream_t stream)
{
    const float* x     = (const float*)d_in[0];
    const float* W     = (const float*)d_in[1];
    const float* bias  = (const float*)d_in[2];
    const float* gamma = (const float*)d_in[3];
    const float* beta  = (const float*)d_in[4];
    const int*   idx   = (const int*)d_in[5];
    float* out = (float*)d_out;

    fused_encoder_kernel<<<dim3(64), dim3(1024), 0, stream>>>(
        x, W, bias, gamma, beta, idx, out);
}